// Round 10
// baseline (123.225 us; speedup 1.0000x reference)
//
#include <hip/hip_runtime.h>
#include <hip/hip_bf16.h>
#include <math.h>

#define BB 64
#define NN 1024
#define EPSV 1e-5f

typedef unsigned short u16;
typedef __attribute__((ext_vector_type(8))) short short8;
typedef __attribute__((ext_vector_type(4))) float f32x4;

#define GLOBAL_AS __attribute__((address_space(1)))
#define LDS_AS __attribute__((address_space(3)))

static __device__ __forceinline__ void gload_lds16(const void* g, void* l) {
  __builtin_amdgcn_global_load_lds((const GLOBAL_AS unsigned int*)g,
                                   (LDS_AS unsigned int*)l, 16, 0, 0);
}

static __device__ __forceinline__ u16 f2bf(float f) {
  __hip_bfloat16 h = __float2bfloat16(f);   // RNE
  union { __hip_bfloat16 h; u16 s; } u; u.h = h; return u.s;
}
static __device__ __forceinline__ float bf2f(u16 s) {
  unsigned int u = ((unsigned int)s) << 16;
  union { unsigned int u; float f; } c; c.u = u; return c.f;
}

// ---------------------------------------------------------------------------
// prep: blocks 0..BB-1 normalize e -> XC0 (B,16,N) + XN0 (B,N,16) bf16,
// channels 1..15 zero (vectorized).  Block BB converts W0/W1/W2 to bf16
// (Wp0 zero-padded into the K=32 cat frame: k=0 -> x ch0, k=16 -> t ch0).
// ---------------------------------------------------------------------------
__global__ __launch_bounds__(256) void prep_kernel(
    const float* __restrict__ e,
    const float* __restrict__ W0, const float* __restrict__ W1,
    const float* __restrict__ W2,
    u16* __restrict__ XC0, u16* __restrict__ XN0,
    u16* __restrict__ Wp0, u16* __restrict__ Wp1, u16* __restrict__ Wp2) {
  int b = blockIdx.x;
  int tid = threadIdx.x;
  __shared__ float row[NN];
  __shared__ float red[256];

  if (b == BB) {  // weight conversion block
    for (int i = tid; i < 32 * 32; i += 256) {
      int o = i >> 5, k = i & 31;
      float v = (k == 0) ? W0[o * 2] : (k == 16) ? W0[o * 2 + 1] : 0.f;
      Wp0[i] = f2bf(v);
    }
    for (int i = tid; i < 64 * 64; i += 256) Wp1[i] = f2bf(W1[i]);
    for (int i = tid; i < 64 * 128; i += 256) Wp2[i] = f2bf(W2[i]);
    return;
  }

  const float* er = e + (size_t)b * NN;
  float s = 0.f;
  for (int i = tid; i < NN; i += 256) { float v = er[i]; row[i] = v; s += v; }
  red[tid] = s; __syncthreads();
  for (int off = 128; off > 0; off >>= 1) {
    if (tid < off) red[tid] += red[tid + off];
    __syncthreads();
  }
  float mu = red[0] * (1.f / NN);
  __syncthreads();
  float s2 = 0.f;
  for (int i = tid; i < NN; i += 256) { float d = row[i] - mu; s2 += d * d; }
  red[tid] = s2; __syncthreads();
  for (int off = 128; off > 0; off >>= 1) {
    if (tid < off) red[tid] += red[tid + off];
    __syncthreads();
  }
  float sd = sqrtf(red[0] * (1.f / NN));
  float inv = 1.f / (sd + EPSV);

  const short8 zz = (short8){0, 0, 0, 0, 0, 0, 0, 0};
  for (int i = tid; i < NN; i += 256) {
    float v = (row[i] - mu) * inv;
    u16 bits = f2bf(v);
    XC0[(size_t)b * 16 * NN + i] = bits;
    short8 a = zz;
    a[0] = (short)bits;
    *(short8*)&XN0[((size_t)b * NN + i) * 16] = a;
    *(short8*)&XN0[((size_t)b * NN + i) * 16 + 8] = zz;
  }
  // zero channels 1..15, vectorized (15*NN/8 = 1920 short8 stores)
  for (int v = tid; v < 15 * NN / 8; v += 256)
    *(short8*)&XC0[(size_t)b * 16 * NN + NN + v * 8] = zz;
}

// ---------------------------------------------------------------------------
// fused layer:  gather (t^T = adj @ x^T, adj generated in registers in MFMA
// A-frag layout; B staged from channel-major XC via global_load_lds,
// double-buffered, NT nodes per macro-step) THEN projection (MFMA over
// cat=[x|t]) in the SAME block.  t never touches global memory.
// Phase 2: W read straight into per-lane B-frag registers from global
// (L2-hot, no LDS staging); XN prefetched into registers before t-spill.
//   phase1 LDS: [pe 8K | slab 2*NT*CE*2B]
//   phase2 LDS: [cat 64*S*2B], zt overlays cat after proj A-reads.
// Writes ZN (B,N,O) node-major and ZC (B,O,N) channel-major.
// ---------------------------------------------------------------------------
template<int CE, int O, int NT>
__global__ __launch_bounds__(256, 4) void fused_kernel(
    const u16* __restrict__ XC,     // (B,CE,N) bf16
    const u16* __restrict__ XN,     // (B,N,CE) bf16
    const float* __restrict__ phi,  // (B,N)
    const float* __restrict__ eta,  // (B,N)
    const u16* __restrict__ Wp,     // (O,2CE) bf16
    const float* __restrict__ bias, // (O)
    u16* __restrict__ ZN,           // (B,N,O)
    u16* __restrict__ ZC)           // (B,O,N)
{
  constexpr int NCT = CE / 16;          // B-tiles per wave in gather
  constexpr int SLABV = NT * CE / 8;    // 16B vectors per slab
  constexpr int KW = 2 * CE;
  constexpr int S = KW + 8;             // padded LDS stride (u16)
  constexpr int OT = O / 16;
  constexpr int KS = KW / 32;
  constexpr int STEPS = NN / NT;
  constexpr int KCN = NT / 32;

  constexpr int PH1 = (int)sizeof(float2) * NN + 2 * NT * CE * 2;
  constexpr int PH2 = 64 * S * 2;
  constexpr int ZTS = 64 * (O + 8) * 2;
  constexpr int SM0 = PH1 > PH2 ? PH1 : PH2;
  constexpr int SM = SM0 > ZTS ? SM0 : ZTS;
  __shared__ __align__(16) char smem[SM];
  float2* pe = (float2*)smem;
  u16* slab0 = (u16*)(smem + sizeof(float2) * NN);
  u16* slab1 = slab0 + NT * CE;
  u16* cat = (u16*)smem;
  u16* zt  = (u16*)smem;                // overlays cat after proj A-reads

  int b = blockIdx.y;
  int m0 = blockIdx.x * 64;
  int tid = threadIdx.x;
  int lane = tid & 63, w = tid >> 6, g = lane >> 4, cl = lane & 15;

  const float* phb = phi + (size_t)b * NN;
  const float* etb = eta + (size_t)b * NN;
  for (int i = tid; i < NN; i += 256)
    pe[i] = make_float2(phb[i], etb[i]);

  int m_lane = m0 + w * 16 + cl;
  float phm = phb[m_lane];
  float etm = etb[m_lane];

  f32x4 acc[NCT];
#pragma unroll
  for (int ci = 0; ci < NCT; ++ci) acc[ci] = (f32x4){0.f, 0.f, 0.f, 0.f};

  const u16* xb = XC + (size_t)b * CE * NN;

  for (int v = tid; v < SLABV; v += 256) {
    int gg = v / CE, cc = v % CE;
    gload_lds16(xb + (size_t)cc * NN + gg * 8, slab0 + v * 8);
  }
  __syncthreads();

  for (int s = 0; s < STEPS; ++s) {
    u16* curp = (s & 1) ? slab1 : slab0;
    u16* nxtp = (s & 1) ? slab0 : slab1;
    if (s + 1 < STEPS) {
      for (int v = tid; v < SLABV; v += 256) {
        int gg = v / CE, cc = v % CE;
        gload_lds16(xb + (size_t)cc * NN + (s + 1) * NT + gg * 8, nxtp + v * 8);
      }
    }
    int n0 = s * NT;
#pragma unroll
    for (int kc = 0; kc < KCN; ++kc) {
      const float2* pp = &pe[n0 + kc * 32 + 8 * g];
      union { short8 v; u16 h[8]; } af;
#pragma unroll
      for (int j = 0; j < 8; ++j) {
        float2 q = pp[j];
        float dp = q.x - phm;
        float de = q.y - etm;
        float d2 = fmaf(dp, dp, de * de);
        af.h[j] = f2bf(__expf(-d2));
      }
#pragma unroll
      for (int ci = 0; ci < NCT; ++ci) {
        const short8* bp =
            (const short8*)&curp[((kc * 4 + g) * CE + ci * 16 + cl) * 8];
        acc[ci] = __builtin_amdgcn_mfma_f32_16x16x32_bf16(af.v, *bp, acc[ci], 0, 0, 0);
      }
    }
    __syncthreads();
  }

  // ---- phase 2: projection (pe/slab dead; cat overlays) ----
  // issue XN prefetch (regs) — latency hides under t-spill + barrier
  constexpr int CV = CE / 8;
  constexpr int NXN = (64 * CV + 255) / 256;
  constexpr bool XFULL = (64 * CV) % 256 == 0;
  short8 xnr[NXN];
#pragma unroll
  for (int i = 0; i < NXN; ++i) {
    int v = tid + i * 256;
    if (XFULL || v < 64 * CV) {
      int m = v / CV, cv = v % CV;
      xnr[i] = *(const short8*)&XN[((size_t)b * NN + m0 + m) * CE + cv * 8];
    }
  }
  // bias (hoisted)
  float bz[OT];
#pragma unroll
  for (int oi = 0; oi < OT; ++oi) bz[oi] = bias[oi * 16 + cl];

  // t part from acc regs (D layout: row=(lane>>4)*4+r, col=lane&15)
#pragma unroll
  for (int ci = 0; ci < NCT; ++ci)
#pragma unroll
    for (int r = 0; r < 4; ++r) {
      int m = w * 16 + g * 4 + r;
      cat[m * S + CE + ci * 16 + cl] = f2bf(acc[ci][r]);
    }
  // x part from prefetched regs
#pragma unroll
  for (int i = 0; i < NXN; ++i) {
    int v = tid + i * 256;
    if (XFULL || v < 64 * CV) {
      int m = v / CV, cv = v % CV;
      *(short8*)&cat[m * S + cv * 8] = xnr[i];
    }
  }
  __syncthreads();

  // A-frags from cat
  short8 afp[KS];
#pragma unroll
  for (int kk = 0; kk < KS; ++kk)
    afp[kk] = *(const short8*)&cat[(w * 16 + cl) * S + kk * 32 + g * 8];

  // W direct from global into per-lane B-frags, batched to cap VGPRs
  constexpr int OB = (8 / KS) < OT ? (8 / KS) : OT;   // oi per batch
  f32x4 pacc[OT];
#pragma unroll
  for (int oi = 0; oi < OT; ++oi) pacc[oi] = (f32x4){0.f, 0.f, 0.f, 0.f};
#pragma unroll
  for (int ob = 0; ob < OT; ob += OB) {
    short8 wfr[OB][KS];
#pragma unroll
    for (int oi = 0; oi < OB; ++oi)
#pragma unroll
      for (int kk = 0; kk < KS; ++kk)
        wfr[oi][kk] = *(const short8*)&Wp[((ob + oi) * 16 + cl) * KW + kk * 32 + g * 8];
#pragma unroll
    for (int oi = 0; oi < OB; ++oi)
#pragma unroll
      for (int kk = 0; kk < KS; ++kk)
        pacc[ob + oi] = __builtin_amdgcn_mfma_f32_16x16x32_bf16(
            afp[kk], wfr[oi][kk], pacc[ob + oi], 0, 0, 0);
  }
  __syncthreads();  // all cat reads done before zt overlay

#pragma unroll
  for (int oi = 0; oi < OT; ++oi) {
#pragma unroll
    for (int r = 0; r < 4; ++r) {
      float z = fmaxf(pacc[oi][r] + bz[oi], 0.f);   // relu (all fused layers)
      u16 zb = f2bf(z);
      int m = w * 16 + 4 * g + r;
      ZN[((size_t)b * NN + m0 + m) * O + oi * 16 + cl] = zb;
      zt[m * (O + 8) + oi * 16 + cl] = zb;
    }
  }
  __syncthreads();
  for (int idx = tid; idx < 64 * O; idx += 256) {
    int m = idx & 63, o = idx >> 6;
    ZC[((size_t)b * O + o) * NN + m0 + m] = zt[m * (O + 8) + o];
  }
}

// ---------------------------------------------------------------------------
// fused last layer: gather (CE=64) + vectorized dot with W3 (O=1) + partial
// ---------------------------------------------------------------------------
__global__ __launch_bounds__(256, 4) void fused_last_kernel(
    const u16* __restrict__ XC,     // (B,64,N)
    const u16* __restrict__ XN,     // (B,N,64)
    const float* __restrict__ phi,
    const float* __restrict__ eta,
    const float* __restrict__ W3,   // (1,128) fp32
    const float* __restrict__ b3,
    float* __restrict__ partial)    // (B,16)
{
  constexpr int CE = 64, NCT = 4, NT = 64;
  constexpr int SLABV = NT * CE / 8;
  constexpr int S = 136;            // cat stride (2*CE + 8)

  constexpr int PH1 = (int)sizeof(float2) * NN + 2 * NT * CE * 2;  // 24.5KB
  __shared__ __align__(16) char smem[PH1];
  float2* pe = (float2*)smem;
  u16* slab0 = (u16*)(smem + sizeof(float2) * NN);
  u16* slab1 = slab0 + NT * CE;
  u16* cat = (u16*)smem;            // 64*S*2 = 17408B, overlays phase1
  __shared__ float sW[128];
  __shared__ float red[256];

  int b = blockIdx.y;
  int m0 = blockIdx.x * 64;
  int tid = threadIdx.x;
  int lane = tid & 63, w = tid >> 6, g = lane >> 4, cl = lane & 15;

  const float* phb = phi + (size_t)b * NN;
  const float* etb = eta + (size_t)b * NN;
  for (int i = tid; i < NN; i += 256)
    pe[i] = make_float2(phb[i], etb[i]);
  if (tid < 128) sW[tid] = W3[tid];

  int m_lane = m0 + w * 16 + cl;
  float phm = phb[m_lane];
  float etm = etb[m_lane];

  f32x4 acc[NCT];
#pragma unroll
  for (int ci = 0; ci < NCT; ++ci) acc[ci] = (f32x4){0.f, 0.f, 0.f, 0.f};

  const u16* xb = XC + (size_t)b * CE * NN;

  for (int v = tid; v < SLABV; v += 256) {
    int gg = v / CE, cc = v % CE;
    gload_lds16(xb + (size_t)cc * NN + gg * 8, slab0 + v * 8);
  }
  __syncthreads();

  for (int s = 0; s < NN / NT; ++s) {
    u16* curp = (s & 1) ? slab1 : slab0;
    u16* nxtp = (s & 1) ? slab0 : slab1;
    if (s + 1 < NN / NT) {
      for (int v = tid; v < SLABV; v += 256) {
        int gg = v / CE, cc = v % CE;
        gload_lds16(xb + (size_t)cc * NN + (s + 1) * NT + gg * 8, nxtp + v * 8);
      }
    }
    int n0 = s * NT;
#pragma unroll
    for (int kc = 0; kc < NT / 32; ++kc) {
      const float2* pp = &pe[n0 + kc * 32 + 8 * g];
      union { short8 v; u16 h[8]; } af;
#pragma unroll
      for (int j = 0; j < 8; ++j) {
        float2 q = pp[j];
        float dp = q.x - phm;
        float de = q.y - etm;
        float d2 = fmaf(dp, dp, de * de);
        af.h[j] = f2bf(__expf(-d2));
      }
#pragma unroll
      for (int ci = 0; ci < NCT; ++ci) {
        const short8* bp =
            (const short8*)&curp[((kc * 4 + g) * CE + ci * 16 + cl) * 8];
        acc[ci] = __builtin_amdgcn_mfma_f32_16x16x32_bf16(af.v, *bp, acc[ci], 0, 0, 0);
      }
    }
    __syncthreads();
  }

  // ---- phase 2: z[m] = W3 . cat[m] ; partial = sum_m z[m] ----
  // XN prefetch into regs (2 vectors/thread), hides under t-spill
  short8 xnr0, xnr1;
  {
    int v0 = tid, v1 = tid + 256;
    int ma = v0 >> 3, ca = v0 & 7, mb = v1 >> 3, cb = v1 & 7;
    xnr0 = *(const short8*)&XN[((size_t)b * NN + m0 + ma) * CE + ca * 8];
    xnr1 = *(const short8*)&XN[((size_t)b * NN + m0 + mb) * CE + cb * 8];
  }
#pragma unroll
  for (int ci = 0; ci < NCT; ++ci)
#pragma unroll
    for (int r = 0; r < 4; ++r) {
      int m = w * 16 + g * 4 + r;
      cat[m * S + CE + ci * 16 + cl] = f2bf(acc[ci][r]);
    }
  {
    int v0 = tid, v1 = tid + 256;
    int ma = v0 >> 3, ca = v0 & 7, mb = v1 >> 3, cb = v1 & 7;
    *(short8*)&cat[ma * S + ca * 8] = xnr0;
    *(short8*)&cat[mb * S + cb * 8] = xnr1;
  }
  __syncthreads();

  int m = tid & 63, q = tid >> 6;
  float sacc = 0.f;
#pragma unroll
  for (int v = 0; v < 4; ++v) {
    short8 cv = *(const short8*)&cat[m * S + q * 32 + v * 8];
#pragma unroll
    for (int j = 0; j < 8; ++j)
      sacc = fmaf(sW[q * 32 + v * 8 + j], bf2f((u16)cv[j]), sacc);
  }
  red[tid] = sacc; __syncthreads();
  for (int off = 128; off > 0; off >>= 1) {
    if (tid < off) red[tid] += red[tid + off];
    __syncthreads();
  }
  if (tid == 0)
    partial[b * 16 + blockIdx.x] = red[0] + 64.f * b3[0];
}

// ---------------------------------------------------------------------------
// final: out[b] = sigmoid( sum_i partial[b][i] / N )
// ---------------------------------------------------------------------------
__global__ __launch_bounds__(64) void final_kernel(const float* __restrict__ partial,
                                                   float* __restrict__ out) {
  int b = blockIdx.x;
  int lane = threadIdx.x;
  float v = (lane < 16) ? partial[b * 16 + lane] : 0.f;
#pragma unroll
  for (int off = 8; off > 0; off >>= 1) v += __shfl_down(v, off);
  if (lane == 0) out[b] = 1.f / (1.f + __expf(-(v * (1.f / NN))));
}

// ---------------------------------------------------------------------------
extern "C" void kernel_launch(void* const* d_in, const int* in_sizes, int n_in,
                              void* d_out, int out_size, void* d_ws, size_t ws_size,
                              hipStream_t stream) {
  const float* e   = (const float*)d_in[0];
  const float* phi = (const float*)d_in[1];
  const float* eta = (const float*)d_in[2];
  const float* W0  = (const float*)d_in[3];
  const float* b0  = (const float*)d_in[4];
  const float* W1  = (const float*)d_in[5];
  const float* b1  = (const float*)d_in[6];
  const float* W2  = (const float*)d_in[7];
  const float* b2  = (const float*)d_in[8];
  const float* W3  = (const float*)d_in[9];
  const float* b3  = (const float*)d_in[10];

  // ws layout:
  //  [0, 8M)  PB partials (B*16 f32) at offset 0; rest free
  //  [ 8,10M) XC0 (B,16,N)   [10,12M) XN0 (B,N,16)
  //  [12,16M) XC1 (B,32,N)   [16,20M) XN1 (B,N,32)
  //  [20,28M) XC2 (B,64,N)   [28,36M) XN2 (B,N,64)
  //  [ 8,16M) XC3 (B,64,N)  (overlays XC0/XN0/XC1 — all dead by layer 2)
  //  [36,44M) XN3 (B,N,64)
  //  [44M..)  Wp0 (32x32), Wp1 (64x64), Wp2 (64x128) bf16
  char* wsb = (char*)d_ws;
  const size_t MB = 1u << 20;
  float* PB = (float*)(wsb);
  u16* XC0 = (u16*)(wsb + 8 * MB);
  u16* XN0 = (u16*)(wsb + 10 * MB);
  u16* XC1 = (u16*)(wsb + 12 * MB);
  u16* XN1 = (u16*)(wsb + 16 * MB);
  u16* XC2 = (u16*)(wsb + 20 * MB);
  u16* XN2 = (u16*)(wsb + 28 * MB);
  u16* XC3 = (u16*)(wsb + 8 * MB);
  u16* XN3 = (u16*)(wsb + 36 * MB);
  u16* Wp0 = (u16*)(wsb + 44 * MB);
  u16* Wp1 = Wp0 + 32 * 32;
  u16* Wp2 = Wp1 + 64 * 64;

  dim3 blk(256);
  dim3 gg(NN / 64, BB);   // 1024 blocks = exactly 4 blocks/CU

  prep_kernel<<<BB + 1, blk, 0, stream>>>(e, W0, W1, W2, XC0, XN0, Wp0, Wp1, Wp2);

  // Layer 0: CE=16 (C=1 padded) -> O=32, NT=128
  fused_kernel<16, 32, 128><<<gg, blk, 0, stream>>>(XC0, XN0, phi, eta, Wp0, b0, XN1, XC1);
  // Layer 1: CE=32 -> O=64, NT=128
  fused_kernel<32, 64, 128><<<gg, blk, 0, stream>>>(XC1, XN1, phi, eta, Wp1, b1, XN2, XC2);
  // Layer 2: CE=64 -> O=64, NT=64
  fused_kernel<64, 64, 64><<<gg, blk, 0, stream>>>(XC2, XN2, phi, eta, Wp2, b2, XN3, XC3);
  // Layer 3: CE=64 -> O=1, fused dot + partials
  fused_last_kernel<<<gg, blk, 0, stream>>>(XC3, XN3, phi, eta, W3, b3, PB);

  final_kernel<<<BB, dim3(64), 0, stream>>>(PB, (float*)d_out);
}

// Round 11
// 119.688 us; speedup vs baseline: 1.0296x; 1.0296x over previous
//
#include <hip/hip_runtime.h>
#include <hip/hip_bf16.h>
#include <math.h>

#define BB 64
#define NN 1024
#define EPSV 1e-5f

typedef unsigned short u16;
typedef __attribute__((ext_vector_type(8))) short short8;
typedef __attribute__((ext_vector_type(4))) float f32x4;

#define GLOBAL_AS __attribute__((address_space(1)))
#define LDS_AS __attribute__((address_space(3)))

// sqrt(log2(e)): pre-scaling phi/eta by this makes dp^2+de^2 already in
// log2 units, so adj = exp2(-(dp^2+de^2)) with no per-entry multiply.
#define SCL 1.20112240878645f

static __device__ __forceinline__ void gload_lds16(const void* g, void* l) {
  __builtin_amdgcn_global_load_lds((const GLOBAL_AS unsigned int*)g,
                                   (LDS_AS unsigned int*)l, 16, 0, 0);
}

static __device__ __forceinline__ u16 f2bf(float f) {
  __hip_bfloat16 h = __float2bfloat16(f);   // RNE
  union { __hip_bfloat16 h; u16 s; } u; u.h = h; return u.s;
}
static __device__ __forceinline__ float bf2f(u16 s) {
  unsigned int u = ((unsigned int)s) << 16;
  union { unsigned int u; float f; } c; c.u = u; return c.f;
}

// adj entry from pre-scaled deltas: exp2(-(dp*dp+de*de)), negation folded
// into fma/mul input modifiers (free).
static __device__ __forceinline__ float expn2(float dp, float de) {
#if __has_builtin(__builtin_amdgcn_exp2f)
  return __builtin_amdgcn_exp2f(fmaf(-dp, dp, -(de * de)));
#else
  return exp2f(fmaf(-dp, dp, -(de * de)));
#endif
}

// ---------------------------------------------------------------------------
// fused0: per-block batch-normalize e (redundant per block, cheap) + rank-2
// layer 0 (C=1 -> O=32) with scalar fp32 gather (4 lanes per m-row, 256 n
// each), writing ZN1 (B,N,32) + ZC1 (B,32,N).  Blocks (x=0,y=0/1) also
// convert W1/W2 to bf16.  No XC0/XN0, no MFMA, no prep kernel.
// ---------------------------------------------------------------------------
__global__ __launch_bounds__(256, 4) void fused0_kernel(
    const float* __restrict__ e,
    const float* __restrict__ phi, const float* __restrict__ eta,
    const float* __restrict__ W0, const float* __restrict__ b0,
    const float* __restrict__ W1, const float* __restrict__ W2,
    u16* __restrict__ Wp1, u16* __restrict__ Wp2,
    u16* __restrict__ ZN,           // (B,N,32)
    u16* __restrict__ ZC)           // (B,32,N)
{
  __shared__ float x0[NN];          // 4KB normalized e
  __shared__ float2 pe[NN];         // 8KB pre-scaled (phi,eta)
  __shared__ float red[256];
  __shared__ u16 zt[64 * 40];       // transpose buffer (stride 40)

  int b = blockIdx.y;
  int m0 = blockIdx.x * 64;
  int tid = threadIdx.x;

  // weight conversion piggyback (done once; all fused0 blocks finish before L1)
  if (blockIdx.x == 0 && b == 0)
    for (int i = tid; i < 64 * 64; i += 256) Wp1[i] = f2bf(W1[i]);
  if (blockIdx.x == 0 && b == 1)
    for (int i = tid; i < 64 * 128; i += 256) Wp2[i] = f2bf(W2[i]);

  const float* er = e + (size_t)b * NN;
  const float* phb = phi + (size_t)b * NN;
  const float* etb = eta + (size_t)b * NN;

  float s = 0.f;
  for (int i = tid; i < NN; i += 256) {
    float v = er[i]; x0[i] = v; s += v;
    pe[i] = make_float2(phb[i] * SCL, etb[i] * SCL);
  }
  red[tid] = s; __syncthreads();
  for (int off = 128; off > 0; off >>= 1) {
    if (tid < off) red[tid] += red[tid + off];
    __syncthreads();
  }
  float mu = red[0] * (1.f / NN);
  __syncthreads();
  float s2 = 0.f;
  for (int i = tid; i < NN; i += 256) { float d = x0[i] - mu; s2 += d * d; }
  red[tid] = s2; __syncthreads();
  for (int off = 128; off > 0; off >>= 1) {
    if (tid < off) red[tid] += red[tid + off];
    __syncthreads();
  }
  float sd = sqrtf(red[0] * (1.f / NN));
  float inv = 1.f / (sd + EPSV);
  for (int i = tid; i < NN; i += 256) x0[i] = (x0[i] - mu) * inv;
  __syncthreads();

  // scalar gather: t0[m] = sum_n adj[m][n] * x0[n], 4 lanes per m
  int mi = tid >> 2;                // 0..63
  int q = tid & 3;                  // n-quarter
  int m = m0 + mi;
  float phm = pe[m].x, etm = pe[m].y;

  const float2* pp = &pe[q * 256];
  const float* xx = &x0[q * 256];
  float t0a = 0.f, t0b = 0.f;
#pragma unroll 4
  for (int n = 0; n < 256; n += 2) {
    float2 qa = pp[n], qb = pp[n + 1];
    float dpa = qa.x - phm, dea = qa.y - etm;
    float dpb = qb.x - phm, deb = qb.y - etm;
    t0a = fmaf(expn2(dpa, dea), xx[n], t0a);
    t0b = fmaf(expn2(dpb, deb), xx[n + 1], t0b);
  }
  float t0 = t0a + t0b;
  t0 += __shfl_xor(t0, 1);
  t0 += __shfl_xor(t0, 2);

  // rank-2 projection: z[o] = relu(W0[o][0]*x0[m] + W0[o][1]*t0 + b0[o])
  float x0m = x0[m];
  union { short8 v; u16 h[8]; } zrow;
#pragma unroll
  for (int oj = 0; oj < 8; ++oj) {
    int o = q * 8 + oj;
    float z = fmaf(W0[o * 2], x0m, fmaf(W0[o * 2 + 1], t0, b0[o]));
    zrow.h[oj] = f2bf(fmaxf(z, 0.f));
  }
  *(short8*)&ZN[((size_t)b * NN + m) * 32 + q * 8] = zrow.v;
  *(short8*)&zt[mi * 40 + q * 8] = zrow.v;
  __syncthreads();
  for (int idx = tid; idx < 64 * 32; idx += 256) {
    int mm = idx & 63, o = idx >> 6;
    ZC[((size_t)b * 32 + o) * NN + m0 + mm] = zt[mm * 40 + o];
  }
}

// ---------------------------------------------------------------------------
// fused layer (L1/L2): gather (adj generated in registers in MFMA A-frag
// layout via exp2 of pre-scaled deltas; B staged from channel-major XC via
// global_load_lds, NT-node double-buffered slabs) THEN projection MFMA, in
// the same block.  Writes ZN (B,N,O) + ZC (B,O,N).
// ---------------------------------------------------------------------------
template<int CE, int O, int NT>
__global__ __launch_bounds__(256, 4) void fused_kernel(
    const u16* __restrict__ XC,     // (B,CE,N) bf16
    const u16* __restrict__ XN,     // (B,N,CE) bf16
    const float* __restrict__ phi,  // (B,N)
    const float* __restrict__ eta,  // (B,N)
    const u16* __restrict__ Wp,     // (O,2CE) bf16
    const float* __restrict__ bias, // (O)
    u16* __restrict__ ZN,           // (B,N,O)
    u16* __restrict__ ZC)           // (B,O,N)
{
  constexpr int NCT = CE / 16;
  constexpr int SLABV = NT * CE / 8;
  constexpr int KW = 2 * CE;
  constexpr int S = KW + 8;
  constexpr int OT = O / 16;
  constexpr int KS = KW / 32;
  constexpr int STEPS = NN / NT;
  constexpr int KCN = NT / 32;

  constexpr int PH1 = (int)sizeof(float2) * NN + 2 * NT * CE * 2;
  constexpr int PH2 = 64 * S * 2;
  constexpr int ZTS = 64 * (O + 8) * 2;
  constexpr int SM0 = PH1 > PH2 ? PH1 : PH2;
  constexpr int SM = SM0 > ZTS ? SM0 : ZTS;
  __shared__ __align__(16) char smem[SM];
  float2* pe = (float2*)smem;
  u16* slab0 = (u16*)(smem + sizeof(float2) * NN);
  u16* slab1 = slab0 + NT * CE;
  u16* cat = (u16*)smem;
  u16* zt  = (u16*)smem;

  int b = blockIdx.y;
  int m0 = blockIdx.x * 64;
  int tid = threadIdx.x;
  int lane = tid & 63, w = tid >> 6, g = lane >> 4, cl = lane & 15;

  const float* phb = phi + (size_t)b * NN;
  const float* etb = eta + (size_t)b * NN;
  for (int i = tid; i < NN; i += 256)
    pe[i] = make_float2(phb[i] * SCL, etb[i] * SCL);

  int m_lane = m0 + w * 16 + cl;
  float phm = phb[m_lane] * SCL;
  float etm = etb[m_lane] * SCL;

  f32x4 acc[NCT];
#pragma unroll
  for (int ci = 0; ci < NCT; ++ci) acc[ci] = (f32x4){0.f, 0.f, 0.f, 0.f};

  const u16* xb = XC + (size_t)b * CE * NN;

  for (int v = tid; v < SLABV; v += 256) {
    int gg = v / CE, cc = v % CE;
    gload_lds16(xb + (size_t)cc * NN + gg * 8, slab0 + v * 8);
  }
  __syncthreads();

  for (int s = 0; s < STEPS; ++s) {
    u16* curp = (s & 1) ? slab1 : slab0;
    u16* nxtp = (s & 1) ? slab0 : slab1;
    if (s + 1 < STEPS) {
      for (int v = tid; v < SLABV; v += 256) {
        int gg = v / CE, cc = v % CE;
        gload_lds16(xb + (size_t)cc * NN + (s + 1) * NT + gg * 8, nxtp + v * 8);
      }
    }
    int n0 = s * NT;
#pragma unroll
    for (int kc = 0; kc < KCN; ++kc) {
      const float2* pp = &pe[n0 + kc * 32 + 8 * g];
      union { short8 v; u16 h[8]; } af;
#pragma unroll
      for (int j = 0; j < 8; ++j) {
        float2 qq = pp[j];
        af.h[j] = f2bf(expn2(qq.x - phm, qq.y - etm));
      }
#pragma unroll
      for (int ci = 0; ci < NCT; ++ci) {
        const short8* bp =
            (const short8*)&curp[((kc * 4 + g) * CE + ci * 16 + cl) * 8];
        acc[ci] = __builtin_amdgcn_mfma_f32_16x16x32_bf16(af.v, *bp, acc[ci], 0, 0, 0);
      }
    }
    __syncthreads();
  }

  // ---- phase 2: projection ----
  constexpr int CV = CE / 8;
  constexpr int NXN = (64 * CV + 255) / 256;
  constexpr bool XFULL = (64 * CV) % 256 == 0;
  short8 xnr[NXN];
#pragma unroll
  for (int i = 0; i < NXN; ++i) {
    int v = tid + i * 256;
    if (XFULL || v < 64 * CV) {
      int m = v / CV, cv = v % CV;
      xnr[i] = *(const short8*)&XN[((size_t)b * NN + m0 + m) * CE + cv * 8];
    }
  }
  float bz[OT];
#pragma unroll
  for (int oi = 0; oi < OT; ++oi) bz[oi] = bias[oi * 16 + cl];

#pragma unroll
  for (int ci = 0; ci < NCT; ++ci)
#pragma unroll
    for (int r = 0; r < 4; ++r) {
      int m = w * 16 + g * 4 + r;
      cat[m * S + CE + ci * 16 + cl] = f2bf(acc[ci][r]);
    }
#pragma unroll
  for (int i = 0; i < NXN; ++i) {
    int v = tid + i * 256;
    if (XFULL || v < 64 * CV) {
      int m = v / CV, cv = v % CV;
      *(short8*)&cat[m * S + cv * 8] = xnr[i];
    }
  }
  __syncthreads();

  short8 afp[KS];
#pragma unroll
  for (int kk = 0; kk < KS; ++kk)
    afp[kk] = *(const short8*)&cat[(w * 16 + cl) * S + kk * 32 + g * 8];

  constexpr int OB = (8 / KS) < OT ? (8 / KS) : OT;
  f32x4 pacc[OT];
#pragma unroll
  for (int oi = 0; oi < OT; ++oi) pacc[oi] = (f32x4){0.f, 0.f, 0.f, 0.f};
#pragma unroll
  for (int ob = 0; ob < OT; ob += OB) {
    short8 wfr[OB][KS];
#pragma unroll
    for (int oi = 0; oi < OB; ++oi)
#pragma unroll
      for (int kk = 0; kk < KS; ++kk)
        wfr[oi][kk] = *(const short8*)&Wp[((ob + oi) * 16 + cl) * KW + kk * 32 + g * 8];
#pragma unroll
    for (int oi = 0; oi < OB; ++oi)
#pragma unroll
      for (int kk = 0; kk < KS; ++kk)
        pacc[ob + oi] = __builtin_amdgcn_mfma_f32_16x16x32_bf16(
            afp[kk], wfr[oi][kk], pacc[ob + oi], 0, 0, 0);
  }
  __syncthreads();

#pragma unroll
  for (int oi = 0; oi < OT; ++oi) {
#pragma unroll
    for (int r = 0; r < 4; ++r) {
      float z = fmaxf(pacc[oi][r] + bz[oi], 0.f);
      u16 zb = f2bf(z);
      int m = w * 16 + 4 * g + r;
      ZN[((size_t)b * NN + m0 + m) * O + oi * 16 + cl] = zb;
      zt[m * (O + 8) + oi * 16 + cl] = zb;
    }
  }
  __syncthreads();
  for (int idx = tid; idx < 64 * O; idx += 256) {
    int m = idx & 63, o = idx >> 6;
    ZC[((size_t)b * O + o) * NN + m0 + m] = zt[m * (O + 8) + o];
  }
}

// ---------------------------------------------------------------------------
// fused last layer: gather (CE=64, NT=128) + dot with W3 + block partial.
// sW/red overlaid into smem so LDS stays 40960B -> 4 blocks/CU.
// ---------------------------------------------------------------------------
__global__ __launch_bounds__(256, 4) void fused_last_kernel(
    const u16* __restrict__ XC,     // (B,64,N)
    const u16* __restrict__ XN,     // (B,N,64)
    const float* __restrict__ phi,
    const float* __restrict__ eta,
    const float* __restrict__ W3,   // (1,128) fp32
    const float* __restrict__ b3,
    float* __restrict__ partial)    // (B,16)
{
  constexpr int CE = 64, NCT = 4, NT = 128;
  constexpr int SLABV = NT * CE / 8;
  constexpr int S = 136;            // cat stride (2*CE + 8)
  constexpr int STEPS = NN / NT;

  constexpr int PH1 = (int)sizeof(float2) * NN + 2 * NT * CE * 2;  // 40960
  __shared__ __align__(16) char smem[PH1];
  float2* pe = (float2*)smem;
  u16* slab0 = (u16*)(smem + sizeof(float2) * NN);
  u16* slab1 = slab0 + NT * CE;
  u16* cat = (u16*)smem;                      // 64*136*2 = 17408 B
  float* sW = (float*)(smem + 17408);         // 512 B
  float* red = (float*)(smem + 17408 + 512);  // 1024 B

  int b = blockIdx.y;
  int m0 = blockIdx.x * 64;
  int tid = threadIdx.x;
  int lane = tid & 63, w = tid >> 6, g = lane >> 4, cl = lane & 15;

  const float* phb = phi + (size_t)b * NN;
  const float* etb = eta + (size_t)b * NN;
  for (int i = tid; i < NN; i += 256)
    pe[i] = make_float2(phb[i] * SCL, etb[i] * SCL);

  int m_lane = m0 + w * 16 + cl;
  float phm = phb[m_lane] * SCL;
  float etm = etb[m_lane] * SCL;

  f32x4 acc[NCT];
#pragma unroll
  for (int ci = 0; ci < NCT; ++ci) acc[ci] = (f32x4){0.f, 0.f, 0.f, 0.f};

  const u16* xb = XC + (size_t)b * CE * NN;

  for (int v = tid; v < SLABV; v += 256) {
    int gg = v / CE, cc = v % CE;
    gload_lds16(xb + (size_t)cc * NN + gg * 8, slab0 + v * 8);
  }
  __syncthreads();

  for (int s = 0; s < STEPS; ++s) {
    u16* curp = (s & 1) ? slab1 : slab0;
    u16* nxtp = (s & 1) ? slab0 : slab1;
    if (s + 1 < STEPS) {
      for (int v = tid; v < SLABV; v += 256) {
        int gg = v / CE, cc = v % CE;
        gload_lds16(xb + (size_t)cc * NN + (s + 1) * NT + gg * 8, nxtp + v * 8);
      }
    }
    int n0 = s * NT;
#pragma unroll
    for (int kc = 0; kc < NT / 32; ++kc) {
      const float2* pp = &pe[n0 + kc * 32 + 8 * g];
      union { short8 v; u16 h[8]; } af;
#pragma unroll
      for (int j = 0; j < 8; ++j) {
        float2 qq = pp[j];
        af.h[j] = f2bf(expn2(qq.x - phm, qq.y - etm));
      }
#pragma unroll
      for (int ci = 0; ci < NCT; ++ci) {
        const short8* bp =
            (const short8*)&curp[((kc * 4 + g) * CE + ci * 16 + cl) * 8];
        acc[ci] = __builtin_amdgcn_mfma_f32_16x16x32_bf16(af.v, *bp, acc[ci], 0, 0, 0);
      }
    }
    __syncthreads();
  }

  // ---- phase 2: z[m] = W3 . cat[m] ; partial = sum_m z[m] ----
  short8 xnr0, xnr1;
  {
    int v0 = tid, v1 = tid + 256;
    int ma = v0 >> 3, ca = v0 & 7, mb = v1 >> 3, cb = v1 & 7;
    xnr0 = *(const short8*)&XN[((size_t)b * NN + m0 + ma) * CE + ca * 8];
    xnr1 = *(const short8*)&XN[((size_t)b * NN + m0 + mb) * CE + cb * 8];
  }
  if (tid < 128) sW[tid] = W3[tid];
#pragma unroll
  for (int ci = 0; ci < NCT; ++ci)
#pragma unroll
    for (int r = 0; r < 4; ++r) {
      int m = w * 16 + g * 4 + r;
      cat[m * S + CE + ci * 16 + cl] = f2bf(acc[ci][r]);
    }
  {
    int v0 = tid, v1 = tid + 256;
    int ma = v0 >> 3, ca = v0 & 7, mb = v1 >> 3, cb = v1 & 7;
    *(short8*)&cat[ma * S + ca * 8] = xnr0;
    *(short8*)&cat[mb * S + cb * 8] = xnr1;
  }
  __syncthreads();

  int m = tid & 63, q = tid >> 6;
  float sacc = 0.f;
#pragma unroll
  for (int v = 0; v < 4; ++v) {
    short8 cv = *(const short8*)&cat[m * S + q * 32 + v * 8];
#pragma unroll
    for (int j = 0; j < 8; ++j)
      sacc = fmaf(sW[q * 32 + v * 8 + j], bf2f((u16)cv[j]), sacc);
  }
  red[tid] = sacc; __syncthreads();
  for (int off = 128; off > 0; off >>= 1) {
    if (tid < off) red[tid] += red[tid + off];
    __syncthreads();
  }
  if (tid == 0)
    partial[b * 16 + blockIdx.x] = red[0] + 64.f * b3[0];
}

// ---------------------------------------------------------------------------
// final: out[b] = sigmoid( sum_i partial[b][i] / N )
// ---------------------------------------------------------------------------
__global__ __launch_bounds__(64) void final_kernel(const float* __restrict__ partial,
                                                   float* __restrict__ out) {
  int b = blockIdx.x;
  int lane = threadIdx.x;
  float v = (lane < 16) ? partial[b * 16 + lane] : 0.f;
#pragma unroll
  for (int off = 8; off > 0; off >>= 1) v += __shfl_down(v, off);
  if (lane == 0) out[b] = 1.f / (1.f + __expf(-(v * (1.f / NN))));
}

// ---------------------------------------------------------------------------
extern "C" void kernel_launch(void* const* d_in, const int* in_sizes, int n_in,
                              void* d_out, int out_size, void* d_ws, size_t ws_size,
                              hipStream_t stream) {
  const float* e   = (const float*)d_in[0];
  const float* phi = (const float*)d_in[1];
  const float* eta = (const float*)d_in[2];
  const float* W0  = (const float*)d_in[3];
  const float* b0  = (const float*)d_in[4];
  const float* W1  = (const float*)d_in[5];
  const float* b1  = (const float*)d_in[6];
  const float* W2  = (const float*)d_in[7];
  const float* b2  = (const float*)d_in[8];
  const float* W3  = (const float*)d_in[9];
  const float* b3  = (const float*)d_in[10];

  // ws layout:
  //  [0, 8M)  PB partials (B*16 f32)
  //  [12,16M) XC1 (B,32,N)   [16,20M) XN1 (B,N,32)
  //  [20,28M) XC2 (B,64,N)   [28,36M) XN2 (B,N,64)
  //  [ 8,16M) XC3 (B,64,N)  (overlays XC1 — dead after L1's gather)
  //  [36,44M) XN3 (B,N,64)
  //  [44M..)  Wp1 (64x64), Wp2 (64x128) bf16
  char* wsb = (char*)d_ws;
  const size_t MB = 1u << 20;
  float* PB = (float*)(wsb);
  u16* XC1 = (u16*)(wsb + 12 * MB);
  u16* XN1 = (u16*)(wsb + 16 * MB);
  u16* XC2 = (u16*)(wsb + 20 * MB);
  u16* XN2 = (u16*)(wsb + 28 * MB);
  u16* XC3 = (u16*)(wsb + 8 * MB);
  u16* XN3 = (u16*)(wsb + 36 * MB);
  u16* Wp1 = (u16*)(wsb + 44 * MB);
  u16* Wp2 = Wp1 + 64 * 64;

  dim3 blk(256);
  dim3 gg(NN / 64, BB);   // 1024 blocks = exactly 4 blocks/CU

  // Layer 0: norm + rank-2 scalar gather + proj (writes XN1/XC1), + Wp conv
  fused0_kernel<<<gg, blk, 0, stream>>>(e, phi, eta, W0, b0, W1, W2,
                                        Wp1, Wp2, XN1, XC1);
  // Layer 1: CE=32 -> O=64, NT=128
  fused_kernel<32, 64, 128><<<gg, blk, 0, stream>>>(XC1, XN1, phi, eta, Wp1, b1, XN2, XC2);
  // Layer 2: CE=64 -> O=64, NT=128
  fused_kernel<64, 64, 128><<<gg, blk, 0, stream>>>(XC2, XN2, phi, eta, Wp2, b2, XN3, XC3);
  // Layer 3: CE=64 -> O=1, NT=128, fused dot + partials
  fused_last_kernel<<<gg, blk, 0, stream>>>(XC3, XN3, phi, eta, W3, b3, PB);

  final_kernel<<<BB, dim3(64), 0, stream>>>(PB, (float*)d_out);
}